// Round 13
// baseline (129.784 us; speedup 1.0000x reference)
//
#include <hip/hip_runtime.h>
#include <cstdint>

#define NBATCH 16
#define CCH    384
#define HW     64
#define PLANE  (HW*HW)
#define NTOT   (NBATCH*PLANE)   // 65536 GEMM columns
#define NPLANES (NBATCH*CCH)    // 6144 dw blocks

typedef __attribute__((ext_vector_type(8))) short short8v;
typedef __attribute__((ext_vector_type(4))) float f32x4;

static __device__ __forceinline__ unsigned short f2bf(float f) {
    unsigned int x = __float_as_uint(f);
    unsigned int r = (x + 0x7fffu + ((x >> 16) & 1u)) >> 16;   // RTN-even
    return (unsigned short)r;
}
// packed f32x2 -> bf16x2 (low16 = a, high16 = b), RTE in HW (r9-verified)
static __device__ __forceinline__ unsigned int cvtpk(float a, float b) {
    unsigned int r;
    asm("v_cvt_pk_bf16_f32 %0, %1, %2" : "=v"(r) : "v"(a), "v"(b));
    return r;
}

// scheme-C rotation (r7-verified): closed mod 128, bijective, 16B-aligned
static __device__ __forceinline__ int rotC(int row) {
    return 2 * (row >> 4) + (row & 7);
}

// 8-wide 5x5 window (r9-verified): out[q] = bias + sum x[h+i-2][w0+q+j-2]*w[i][j]
static __device__ __forceinline__ void conv5x5_8(const float* __restrict__ xp, int h, int w0,
                                                 const float* __restrict__ sw0, float bias,
                                                 float out[8]) {
    #pragma unroll
    for (int q = 0; q < 8; ++q) out[q] = bias;
    #pragma unroll
    for (int i = 0; i < 5; ++i) {
        const int rt = h + i - 2;
        float f[16];
        #pragma unroll
        for (int q = 0; q < 4; ++q) {
            const int c0 = w0 - 4 + 4 * q;
            float4 v = make_float4(0.f, 0.f, 0.f, 0.f);
            if ((unsigned)rt < 64u && (unsigned)c0 <= 60u)
                v = *reinterpret_cast<const float4*>(xp + rt * HW + c0);
            f[4*q+0] = v.x; f[4*q+1] = v.y; f[4*q+2] = v.z; f[4*q+3] = v.w;
        }
        #pragma unroll
        for (int j = 0; j < 5; ++j) {
            const float wg = sw0[i * 5 + j];
            #pragma unroll
            for (int q = 0; q < 8; ++q) out[q] += f[q + j + 2] * wg;
        }
    }
}

// ---------------- prep kernel: band frags + bsum + wa_cvt (r11-verified) ----------------
__global__ __launch_bounds__(256)
void prep(const float* __restrict__ w1, const float* __restrict__ b1,
          const float* __restrict__ w2, const float* __restrict__ b2,
          const float* __restrict__ w3, const float* __restrict__ b3,
          const float* __restrict__ w4, const float* __restrict__ b4,
          const float* __restrict__ w5, const float* __restrict__ b5,
          const float* __restrict__ w6, const float* __restrict__ b6,
          const float* __restrict__ wa, unsigned short* __restrict__ waB,
          unsigned short* __restrict__ fragV, unsigned short* __restrict__ fragH,
          float* __restrict__ bsum)
{
    const int tid = threadIdx.x;
    if (blockIdx.x >= CCH) {
        const int i = (blockIdx.x - CCH) * 256 + tid;
        const float4 v = reinterpret_cast<const float4*>(wa)[i];
        ushort4 o;
        o.x = f2bf(v.x); o.y = f2bf(v.y); o.z = f2bf(v.z); o.w = f2bf(v.w);
        reinterpret_cast<ushort4*>(waB)[i] = o;
        return;
    }
    const int c = blockIdx.x;
    __shared__ float swh[21];
    __shared__ float swv[21];

    if (tid < 21) {                            // horizontal: w5(21)+w3(11)+w1(7)
        const int d = tid, dj = d - 10;
        float v = w5[c * 21 + d];
        if (dj >= -5 && dj <= 5) v += w3[c * 11 + dj + 5];
        if (dj >= -3 && dj <= 3) v += w1[c * 7  + dj + 3];
        swh[d] = v;
    } else if (tid >= 32 && tid < 53) {        // vertical: w6(21)+w4(11)+w2(7)
        const int d = tid - 32, di = d - 10;
        float v = w6[c * 21 + d];
        if (di >= -5 && di <= 5) v += w4[c * 11 + di + 5];
        if (di >= -3 && di <= 3) v += w2[c * 7  + di + 3];
        swv[d] = v;
    } else if (tid == 64) {
        bsum[c] = b1[c] + b2[c] + b3[c] + b4[c] + b5[c] + b6[c];
    }
    __syncthreads();

    const int lane = tid & 63;
    const int slot = tid >> 6;      // wid (fragV) / nt (fragH)
    const int l15  = lane & 15;
    const int l16  = lane >> 4;
    const int row  = slot * 16 + l15;           // arow / brow

    #pragma unroll
    for (int kk = 0; kk < 2; ++kk) {
        unsigned short uv[8], uh[8];
        #pragma unroll
        for (int j = 0; j < 8; ++j) {
            const int k = kk * 32 + l16 * 8 + j;
            const int d = k - row + 10;
            const bool ok = (unsigned)d < 21u;
            uv[j] = ok ? f2bf(swv[d]) : (unsigned short)0;
            uh[j] = ok ? f2bf(swh[d]) : (unsigned short)0;
        }
        const size_t idx = (size_t)(((c * 4 + slot) * 2 + kk) * 64 + lane) * 8;
        *reinterpret_cast<uint4*>(fragV + idx) = *reinterpret_cast<const uint4*>(uv);
        *reinterpret_cast<uint4*>(fragH + idx) = *reinterpret_cast<const uint4*>(uh);
    }
}

// ---------------- fused depthwise kernel v10 ----------------
// r11 (89.7us) structure with VGPR diet (target <=64 -> 8 waves/SIMD, LDS-cap 9):
//   - bH loaded INSIDE the nt loop (kills 32 held VGPRs; fragH is L2-hot)
//   - conv as two 8-wide halves, each packed immediately (halves conv live-set)
// Everything else byte-identical to r11.
__global__ __launch_bounds__(256)
void dw_fused(const float* __restrict__ x,
              const float* __restrict__ w0, const float* __restrict__ b0,
              const unsigned short* __restrict__ fragV,
              const unsigned short* __restrict__ fragH,
              const float* __restrict__ bsum,
              unsigned short* __restrict__ spB)
{
    __shared__ char ipR[64 * 128];
    __shared__ char ipT[64 * 128];
    __shared__ float sw0[25];
    __shared__ float sb[2];

    const int tid = threadIdx.x;
    const int n   = blockIdx.x / CCH;
    const int c   = blockIdx.x % CCH;

    const int lane = tid & 63;
    const int wid  = tid >> 6;
    const int l15  = lane & 15;
    const int l16  = lane >> 4;

    // ---- issue aV frag loads immediately (only need c, wid; 8 VGPRs) ----
    short8v aV[2];
    #pragma unroll
    for (int kk = 0; kk < 2; ++kk) {
        const size_t idx = (size_t)(((c * 4 + wid) * 2 + kk) * 64 + lane) * 8;
        aV[kk] = *reinterpret_cast<const short8v*>(fragV + idx);
    }

    // ---- weights: 5x5 + biases ----
    if (tid < 25)       sw0[tid] = w0[c * 25 + tid];
    else if (tid == 25) sb[0] = b0[c];
    else if (tid == 26) sb[1] = bsum[c];
    __syncthreads();   // B1

    const int h  = tid >> 2;        // v5 conv mapping (coalesced; r10 lesson)
    const int p  = tid & 3;
    const int ws = p << 4;

    // ---- 5x5 fp32, two 8-wide halves packed immediately (register-lean) ----
    unsigned int wv[8];
    {
        const float* xp = x + (size_t)blockIdx.x * PLANE;
        const float b0v = sb[0];
        {
            float accA[8];
            conv5x5_8(xp, h, ws, sw0, b0v, accA);
            #pragma unroll
            for (int j = 0; j < 4; ++j) wv[j] = cvtpk(accA[2*j], accA[2*j+1]);
        }
        {
            float accB[8];
            conv5x5_8(xp, h, ws + 8, sw0, b0v, accB);
            #pragma unroll
            for (int j = 0; j < 4; ++j) wv[4 + j] = cvtpk(accB[2*j], accB[2*j+1]);
        }
    }
    // ---- write ipR (vector) + ipT (transposed), v8-exact ----
    {
        const int rot = rotC(h);
        #pragma unroll
        for (int q = 0; q < 2; ++q) {
            const int off = ((ws << 1) + 16 * q + 16 * rot) & 127;
            uint4 u4 = make_uint4(wv[4*q+0], wv[4*q+1], wv[4*q+2], wv[4*q+3]);
            *reinterpret_cast<uint4*>(ipR + h * 128 + off) = u4;
        }
        #pragma unroll
        for (int k = 0; k < 16; ++k) {
            const int w   = ws + k;
            const int off = (2 * h + 16 * rotC(w)) & 127;
            *reinterpret_cast<unsigned short*>(ipT + w * 128 + off) =
                (unsigned short)(wv[k >> 1] >> (16 * (k & 1)));
        }
    }
    __syncthreads();   // B2

    // ---- aH from ipR (v8 pattern; 8 VGPRs) ----
    const int arow = wid * 16 + l15;
    const int rotA = 16 * (2 * wid + (l15 & 7));
    short8v aH[2];
    #pragma unroll
    for (int kk = 0; kk < 2; ++kk) {
        const int off = (kk * 64 + l16 * 16 + rotA) & 127;
        aH[kk] = *reinterpret_cast<const short8v*>(ipR + arow * 128 + off);
    }
    const float bv1 = sb[1];
    unsigned short* op = spB + ((size_t)c * NBATCH + n) * PLANE;

    #pragma unroll
    for (int nt = 0; nt < 4; ++nt) {
        const int brow = nt * 16 + l15;
        const int rotB = 16 * (2 * nt + (l15 & 7));
        f32x4 acc = (f32x4){0.f, 0.f, 0.f, 0.f};
        #pragma unroll
        for (int kk = 0; kk < 2; ++kk) {
            const int off = (kk * 64 + l16 * 16 + rotB) & 127;
            const short8v bV = *reinterpret_cast<const short8v*>(ipT + brow * 128 + off);
            // bH loaded at use (L2-hot; frees 32 held VGPRs vs r11)
            const size_t idx = (size_t)(((c * 4 + nt) * 2 + kk) * 64 + lane) * 8;
            const short8v bH = *reinterpret_cast<const short8v*>(fragH + idx);
            acc = __builtin_amdgcn_mfma_f32_16x16x32_bf16(aV[kk], bV, acc, 0, 0, 0);
            acc = __builtin_amdgcn_mfma_f32_16x16x32_bf16(aH[kk], bH, acc, 0, 0, 0);
        }
        #pragma unroll
        for (int r = 0; r < 4; ++r) {
            const int hh = wid * 16 + 4 * l16 + r;
            const int ww = nt * 16 + l15;
            op[hh * HW + ww] = f2bf(acc[r] + bv1);
        }
    }
}

// ---------------- 1x1 conv as bf16 MFMA GEMM (unchanged) ----------------
__global__ __launch_bounds__(256)
void pw_mfma(const unsigned short* __restrict__ spB,
             const unsigned short* __restrict__ waB,
             const float* __restrict__ ba, float* __restrict__ out)
{
    __shared__ unsigned short As[128 * 64];
    __shared__ unsigned short Bs[128 * 64];

    const int tid  = threadIdx.x;
    const int lane = tid & 63;
    const int wid  = tid >> 6;
    const int wrow = wid >> 1;
    const int wcol = wid & 1;

    const int co0  = blockIdx.y * 128;
    const int col0 = blockIdx.x * 128;

    f32x4 acc[4][4];
    #pragma unroll
    for (int m = 0; m < 4; ++m)
        #pragma unroll
        for (int nn = 0; nn < 4; ++nn) acc[m][nn] = (f32x4){0.f, 0.f, 0.f, 0.f};

    const char* waBb = (const char*)waB;

    for (int kt = 0; kt < 6; ++kt) {
        #pragma unroll
        for (int q = 0; q < 4; ++q) {
            const int L     = (wid * 4 + q) * 1024 + lane * 16;
            const int row   = L >> 7;
            const int kbyte = (L & 127) ^ ((row & 7) << 4);
            const void* src = (const void*)(waBb + (size_t)(co0 + row) * 768 + kt * 128 + kbyte);
            __builtin_amdgcn_global_load_lds(
                (const __attribute__((address_space(1))) void*)src,
                (__attribute__((address_space(3))) void*)((char*)As + (wid * 4 + q) * 1024),
                16, 0, 0);
        }

        #pragma unroll
        for (int j = 0; j < 2; ++j) {
            const int kloc  = j * 32 + 2 * (tid >> 4);
            const int cbase = 8 * (tid & 15);
            const unsigned int* gp =
                (const unsigned int*)(spB + (size_t)(kt * 64 + kloc) * NTOT + col0 + cbase);
            unsigned int g0[4], g1[4];
            *(uint4*)g0 = *(const uint4*)gp;
            *(uint4*)g1 = *(const uint4*)(gp + NTOT / 2);
            #pragma unroll
            for (int r = 0; r < 8; ++r) {
                const unsigned int w0v = g0[r >> 1], w1v = g1[r >> 1];
                const unsigned int lo = (r & 1) ? (w0v >> 16) : (w0v & 0xffffu);
                const unsigned int hi = (r & 1) ? (w1v >> 16) : (w1v & 0xffffu);
                const unsigned int val = lo | (hi << 16);
                const int colL = cbase + r;
                const int s    = (r ^ (tid & 7)) & 7;
                const int byte = colL * 128 + ((kloc * 2) ^ (s << 4));
                *(unsigned int*)((char*)Bs + byte) = val;
            }
        }
        __syncthreads();

        #pragma unroll
        for (int kk = 0; kk < 2; ++kk) {
            short8v aF[4], bF[4];
            const int kbyte = kk * 64 + (lane >> 4) * 16;
            #pragma unroll
            for (int m = 0; m < 4; ++m) {
                const int row = wrow * 64 + m * 16 + (lane & 15);
                aF[m] = *(const short8v*)((const char*)As + row * 128 + (kbyte ^ ((row & 7) << 4)));
            }
            #pragma unroll
            for (int nn = 0; nn < 4; ++nn) {
                const int col = wcol * 64 + nn * 16 + (lane & 15);
                const int s   = ((col & 7) ^ ((col >> 3) & 7)) << 4;
                bF[nn] = *(const short8v*)((const char*)Bs + col * 128 + (kbyte ^ s));
            }
            #pragma unroll
            for (int m = 0; m < 4; ++m)
                #pragma unroll
                for (int nn = 0; nn < 4; ++nn)
                    acc[m][nn] = __builtin_amdgcn_mfma_f32_16x16x32_bf16(
                        aF[m], bF[nn], acc[m][nn], 0, 0, 0);
        }
        __syncthreads();
    }

    const int nb  = col0 >> 12;
    const int px0 = col0 & 4095;
    #pragma unroll
    for (int m = 0; m < 4; ++m) {
        #pragma unroll
        for (int r = 0; r < 4; ++r) {
            const int co = co0 + wrow * 64 + m * 16 + 4 * (lane >> 4) + r;
            const float bv = ba[co];
            float* orow = out + ((size_t)(nb * CCH + co)) * PLANE + px0 + wcol * 64 + (lane & 15);
            #pragma unroll
            for (int nn = 0; nn < 4; ++nn)
                orow[nn * 16] = acc[m][nn][r] + bv;
        }
    }
}

extern "C" void kernel_launch(void* const* d_in, const int* in_sizes, int n_in,
                              void* d_out, int out_size, void* d_ws, size_t ws_size,
                              hipStream_t stream)
{
    const float* x  = (const float*)d_in[0];
    const float* w0 = (const float*)d_in[1];
    const float* b0 = (const float*)d_in[2];
    const float* w1 = (const float*)d_in[3];
    const float* b1 = (const float*)d_in[4];
    const float* w2 = (const float*)d_in[5];
    const float* b2 = (const float*)d_in[6];
    const float* w3 = (const float*)d_in[7];
    const float* b3 = (const float*)d_in[8];
    const float* w4 = (const float*)d_in[9];
    const float* b4 = (const float*)d_in[10];
    const float* w5 = (const float*)d_in[11];
    const float* b5 = (const float*)d_in[12];
    const float* w6 = (const float*)d_in[13];
    const float* b6 = (const float*)d_in[14];
    const float* wa = (const float*)d_in[15];
    const float* ba = (const float*)d_in[16];
    float* out = (float*)d_out;

    char* ws_base = (char*)d_ws;
    unsigned short* spB   = (unsigned short*)ws_base;                    // 50,331,648 B
    unsigned short* waB   = (unsigned short*)(ws_base + 50331648);       //    294,912 B
    unsigned short* fragV = (unsigned short*)(ws_base + 50626560);       //  3,145,728 B
    unsigned short* fragH = (unsigned short*)(ws_base + 53772288);       //  3,145,728 B
    float*          bsum  = (float*)         (ws_base + 56918016);       //      1,536 B

    prep<<<dim3(CCH + 144), 256, 0, stream>>>(
        w1, b1, w2, b2, w3, b3, w4, b4, w5, b5, w6, b6, wa, waB, fragV, fragH, bsum);
    dw_fused<<<dim3(NPLANES), 256, 0, stream>>>(
        x, w0, b0, fragV, fragH, bsum, spB);
    pw_mfma<<<dim3(NTOT / 128, CCH / 128), 256, 0, stream>>>(spB, waB, ba, out);
}

// Round 14
// 125.967 us; speedup vs baseline: 1.0303x; 1.0303x over previous
//
#include <hip/hip_runtime.h>
#include <cstdint>

#define NBATCH 16
#define CCH    384
#define HW     64
#define PLANE  (HW*HW)
#define NTOT   (NBATCH*PLANE)   // 65536 GEMM columns
#define NPLANES (NBATCH*CCH)    // 6144 dw blocks

typedef __attribute__((ext_vector_type(8))) short short8v;
typedef __attribute__((ext_vector_type(4))) float f32x4;

static __device__ __forceinline__ unsigned short f2bf(float f) {
    unsigned int x = __float_as_uint(f);
    unsigned int r = (x + 0x7fffu + ((x >> 16) & 1u)) >> 16;   // RTN-even
    return (unsigned short)r;
}
// packed f32x2 -> bf16x2 (low16 = a, high16 = b), RTE in HW (r9-verified)
static __device__ __forceinline__ unsigned int cvtpk(float a, float b) {
    unsigned int r;
    asm("v_cvt_pk_bf16_f32 %0, %1, %2" : "=v"(r) : "v"(a), "v"(b));
    return r;
}

// scheme-C rotation (r7-verified): closed mod 128, bijective, 16B-aligned
static __device__ __forceinline__ int rotC(int row) {
    return 2 * (row >> 4) + (row & 7);
}

// ---------------- prep kernel: band frags + bsum + wa_cvt (r11-verified) ----------------
__global__ __launch_bounds__(256)
void prep(const float* __restrict__ w1, const float* __restrict__ b1,
          const float* __restrict__ w2, const float* __restrict__ b2,
          const float* __restrict__ w3, const float* __restrict__ b3,
          const float* __restrict__ w4, const float* __restrict__ b4,
          const float* __restrict__ w5, const float* __restrict__ b5,
          const float* __restrict__ w6, const float* __restrict__ b6,
          const float* __restrict__ wa, unsigned short* __restrict__ waB,
          unsigned short* __restrict__ fragV, unsigned short* __restrict__ fragH,
          float* __restrict__ bsum)
{
    const int tid = threadIdx.x;
    if (blockIdx.x >= CCH) {
        const int i = (blockIdx.x - CCH) * 256 + tid;
        const float4 v = reinterpret_cast<const float4*>(wa)[i];
        ushort4 o;
        o.x = f2bf(v.x); o.y = f2bf(v.y); o.z = f2bf(v.z); o.w = f2bf(v.w);
        reinterpret_cast<ushort4*>(waB)[i] = o;
        return;
    }
    const int c = blockIdx.x;
    __shared__ float swh[21];
    __shared__ float swv[21];

    if (tid < 21) {                            // horizontal: w5(21)+w3(11)+w1(7)
        const int d = tid, dj = d - 10;
        float v = w5[c * 21 + d];
        if (dj >= -5 && dj <= 5) v += w3[c * 11 + dj + 5];
        if (dj >= -3 && dj <= 3) v += w1[c * 7  + dj + 3];
        swh[d] = v;
    } else if (tid >= 32 && tid < 53) {        // vertical: w6(21)+w4(11)+w2(7)
        const int d = tid - 32, di = d - 10;
        float v = w6[c * 21 + d];
        if (di >= -5 && di <= 5) v += w4[c * 11 + di + 5];
        if (di >= -3 && di <= 3) v += w2[c * 7  + di + 3];
        swv[d] = v;
    } else if (tid == 64) {
        bsum[c] = b1[c] + b2[c] + b3[c] + b4[c] + b5[c] + b6[c];
    }
    __syncthreads();

    const int lane = tid & 63;
    const int slot = tid >> 6;      // wid (fragV) / nt (fragH)
    const int l15  = lane & 15;
    const int l16  = lane >> 4;
    const int row  = slot * 16 + l15;           // arow / brow

    #pragma unroll
    for (int kk = 0; kk < 2; ++kk) {
        unsigned short uv[8], uh[8];
        #pragma unroll
        for (int j = 0; j < 8; ++j) {
            const int k = kk * 32 + l16 * 8 + j;
            const int d = k - row + 10;
            const bool ok = (unsigned)d < 21u;
            uv[j] = ok ? f2bf(swv[d]) : (unsigned short)0;
            uh[j] = ok ? f2bf(swh[d]) : (unsigned short)0;
        }
        const size_t idx = (size_t)(((c * 4 + slot) * 2 + kk) * 64 + lane) * 8;
        *reinterpret_cast<uint4*>(fragV + idx) = *reinterpret_cast<const uint4*>(uv);
        *reinterpret_cast<uint4*>(fragH + idx) = *reinterpret_cast<const uint4*>(uh);
    }
}

// ---------------- fused depthwise kernel v11 ----------------
// v8 (r11, 89.7us) skeleton with VALU/stall surgery:
//   - w0/b0/bsum via wave-uniform loads -> SGPRs (no sw0/sb LDS, B1 deleted)
//   - branch-free-interior conv: 1 row-predicate per row; col checks only on
//     the 2 edge granules (f[2],f[3] iff p==0; f[20],f[21] iff p==3; f[0,1],
//     f[22,23] dead). All other granules provably in-bounds.
//   - aV issued at entry; bH issued right after cvtpk, HELD across B2 (r13:
//     in-loop bH loads regressed; hold them)
// ipR/ipT/swizzles/MFMA/epilogue byte-identical to r11.
__global__ __launch_bounds__(256)
void dw_fused(const float* __restrict__ x,
              const float* __restrict__ w0, const float* __restrict__ b0,
              const unsigned short* __restrict__ fragV,
              const unsigned short* __restrict__ fragH,
              const float* __restrict__ bsum,
              unsigned short* __restrict__ spB)
{
    __shared__ char ipR[64 * 128];
    __shared__ char ipT[64 * 128];

    const int tid = threadIdx.x;
    const int n   = blockIdx.x / CCH;
    const int c   = blockIdx.x % CCH;

    const int lane = tid & 63;
    const int wid  = tid >> 6;
    const int l15  = lane & 15;
    const int l16  = lane >> 4;

    // ---- issue aV frag loads immediately ----
    short8v aV[2];
    #pragma unroll
    for (int kk = 0; kk < 2; ++kk) {
        const size_t idx = (size_t)(((c * 4 + wid) * 2 + kk) * 64 + lane) * 8;
        aV[kk] = *reinterpret_cast<const short8v*>(fragV + idx);
    }

    // ---- uniform scalars (SGPR path; no LDS, no barrier) ----
    const float b0v = b0[c];
    const float bv1 = bsum[c];

    const int h  = tid >> 2;        // v5 conv mapping (coalesced; r10 lesson)
    const int p  = tid & 3;
    const int ws = p << 4;

    // ---- 5x5 fp32 direct from global, branch-free interior ----
    float acc5[16];
    #pragma unroll
    for (int q = 0; q < 16; ++q) acc5[q] = b0v;
    {
        const float* xp = x + (size_t)blockIdx.x * PLANE;
        #pragma unroll
        for (int i = 0; i < 5; ++i) {
            const int rt = h + i - 2;
            if ((unsigned)rt < 64u) {          // divergent only in edge waves
                const float* row = xp + rt * HW;
                float f[24];
                // granule 0: only f[2],f[3] used; invalid iff p==0
                {
                    const float4 v = *reinterpret_cast<const float4*>(row + (p ? ws - 4 : 0));
                    f[2] = p ? v.z : 0.f;
                    f[3] = p ? v.w : 0.f;
                }
                #pragma unroll
                for (int g = 1; g <= 4; ++g) {  // always in-bounds (ws..ws+12 <= 60)
                    const float4 v = *reinterpret_cast<const float4*>(row + ws - 4 + 4 * g);
                    f[4*g+0] = v.x; f[4*g+1] = v.y; f[4*g+2] = v.z; f[4*g+3] = v.w;
                }
                // granule 5: only f[20],f[21] used; invalid iff p==3
                {
                    const bool ok = (p != 3);
                    const float4 v = *reinterpret_cast<const float4*>(row + (ok ? ws + 16 : 0));
                    f[20] = ok ? v.x : 0.f;
                    f[21] = ok ? v.y : 0.f;
                }
                #pragma unroll
                for (int j = 0; j < 5; ++j) {
                    const float wg = w0[c * 25 + i * 5 + j];   // uniform -> SGPR
                    #pragma unroll
                    for (int q = 0; q < 16; ++q) acc5[q] += f[q + j + 2] * wg;
                }
            }
        }
    }
    // ---- pack bf16 (cvtpk) ----
    unsigned int wv[8];
    #pragma unroll
    for (int j = 0; j < 8; ++j) wv[j] = cvtpk(acc5[2*j], acc5[2*j+1]);

    // ---- issue bH frag loads now (hide under pack stores + barrier) ----
    short8v bH[4][2];
    #pragma unroll
    for (int nt = 0; nt < 4; ++nt)
        #pragma unroll
        for (int kk = 0; kk < 2; ++kk) {
            const size_t idx = (size_t)(((c * 4 + nt) * 2 + kk) * 64 + lane) * 8;
            bH[nt][kk] = *reinterpret_cast<const short8v*>(fragH + idx);
        }

    // ---- write ipR (vector) + ipT (transposed), r11-exact ----
    {
        const int rot = rotC(h);
        #pragma unroll
        for (int q = 0; q < 2; ++q) {
            const int off = ((ws << 1) + 16 * q + 16 * rot) & 127;
            uint4 u4 = make_uint4(wv[4*q+0], wv[4*q+1], wv[4*q+2], wv[4*q+3]);
            *reinterpret_cast<uint4*>(ipR + h * 128 + off) = u4;
        }
        #pragma unroll
        for (int k = 0; k < 16; ++k) {
            const int w   = ws + k;
            const int off = (2 * h + 16 * rotC(w)) & 127;
            *reinterpret_cast<unsigned short*>(ipT + w * 128 + off) =
                (unsigned short)(wv[k >> 1] >> (16 * (k & 1)));
        }
    }
    __syncthreads();   // B2 (the only barrier)

    // ---- aH from ipR ----
    const int arow = wid * 16 + l15;
    const int rotA = 16 * (2 * wid + (l15 & 7));
    short8v aH[2];
    #pragma unroll
    for (int kk = 0; kk < 2; ++kk) {
        const int off = (kk * 64 + l16 * 16 + rotA) & 127;
        aH[kk] = *reinterpret_cast<const short8v*>(ipR + arow * 128 + off);
    }
    unsigned short* op = spB + ((size_t)c * NBATCH + n) * PLANE;

    #pragma unroll
    for (int nt = 0; nt < 4; ++nt) {
        const int brow = nt * 16 + l15;
        const int rotB = 16 * (2 * nt + (l15 & 7));
        f32x4 acc = (f32x4){0.f, 0.f, 0.f, 0.f};
        #pragma unroll
        for (int kk = 0; kk < 2; ++kk) {
            const int off = (kk * 64 + l16 * 16 + rotB) & 127;
            const short8v bV = *reinterpret_cast<const short8v*>(ipT + brow * 128 + off);
            acc = __builtin_amdgcn_mfma_f32_16x16x32_bf16(aV[kk], bV, acc, 0, 0, 0);
            acc = __builtin_amdgcn_mfma_f32_16x16x32_bf16(aH[kk], bH[nt][kk], acc, 0, 0, 0);
        }
        #pragma unroll
        for (int r = 0; r < 4; ++r) {
            const int hh = wid * 16 + 4 * l16 + r;
            const int ww = nt * 16 + l15;
            op[hh * HW + ww] = f2bf(acc[r] + bv1);
        }
    }
}

// ---------------- 1x1 conv as bf16 MFMA GEMM (unchanged) ----------------
__global__ __launch_bounds__(256)
void pw_mfma(const unsigned short* __restrict__ spB,
             const unsigned short* __restrict__ waB,
             const float* __restrict__ ba, float* __restrict__ out)
{
    __shared__ unsigned short As[128 * 64];
    __shared__ unsigned short Bs[128 * 64];

    const int tid  = threadIdx.x;
    const int lane = tid & 63;
    const int wid  = tid >> 6;
    const int wrow = wid >> 1;
    const int wcol = wid & 1;

    const int co0  = blockIdx.y * 128;
    const int col0 = blockIdx.x * 128;

    f32x4 acc[4][4];
    #pragma unroll
    for (int m = 0; m < 4; ++m)
        #pragma unroll
        for (int nn = 0; nn < 4; ++nn) acc[m][nn] = (f32x4){0.f, 0.f, 0.f, 0.f};

    const char* waBb = (const char*)waB;

    for (int kt = 0; kt < 6; ++kt) {
        #pragma unroll
        for (int q = 0; q < 4; ++q) {
            const int L     = (wid * 4 + q) * 1024 + lane * 16;
            const int row   = L >> 7;
            const int kbyte = (L & 127) ^ ((row & 7) << 4);
            const void* src = (const void*)(waBb + (size_t)(co0 + row) * 768 + kt * 128 + kbyte);
            __builtin_amdgcn_global_load_lds(
                (const __attribute__((address_space(1))) void*)src,
                (__attribute__((address_space(3))) void*)((char*)As + (wid * 4 + q) * 1024),
                16, 0, 0);
        }

        #pragma unroll
        for (int j = 0; j < 2; ++j) {
            const int kloc  = j * 32 + 2 * (tid >> 4);
            const int cbase = 8 * (tid & 15);
            const unsigned int* gp =
                (const unsigned int*)(spB + (size_t)(kt * 64 + kloc) * NTOT + col0 + cbase);
            unsigned int g0[4], g1[4];
            *(uint4*)g0 = *(const uint4*)gp;
            *(uint4*)g1 = *(const uint4*)(gp + NTOT / 2);
            #pragma unroll
            for (int r = 0; r < 8; ++r) {
                const unsigned int w0v = g0[r >> 1], w1v = g1[r >> 1];
                const unsigned int lo = (r & 1) ? (w0v >> 16) : (w0v & 0xffffu);
                const unsigned int hi = (r & 1) ? (w1v >> 16) : (w1v & 0xffffu);
                const unsigned int val = lo | (hi << 16);
                const int colL = cbase + r;
                const int s    = (r ^ (tid & 7)) & 7;
                const int byte = colL * 128 + ((kloc * 2) ^ (s << 4));
                *(unsigned int*)((char*)Bs + byte) = val;
            }
        }
        __syncthreads();

        #pragma unroll
        for (int kk = 0; kk < 2; ++kk) {
            short8v aF[4], bF[4];
            const int kbyte = kk * 64 + (lane >> 4) * 16;
            #pragma unroll
            for (int m = 0; m < 4; ++m) {
                const int row = wrow * 64 + m * 16 + (lane & 15);
                aF[m] = *(const short8v*)((const char*)As + row * 128 + (kbyte ^ ((row & 7) << 4)));
            }
            #pragma unroll
            for (int nn = 0; nn < 4; ++nn) {
                const int col = wcol * 64 + nn * 16 + (lane & 15);
                const int s   = ((col & 7) ^ ((col >> 3) & 7)) << 4;
                bF[nn] = *(const short8v*)((const char*)Bs + col * 128 + (kbyte ^ s));
            }
            #pragma unroll
            for (int m = 0; m < 4; ++m)
                #pragma unroll
                for (int nn = 0; nn < 4; ++nn)
                    acc[m][nn] = __builtin_amdgcn_mfma_f32_16x16x32_bf16(
                        aF[m], bF[nn], acc[m][nn], 0, 0, 0);
        }
        __syncthreads();
    }

    const int nb  = col0 >> 12;
    const int px0 = col0 & 4095;
    #pragma unroll
    for (int m = 0; m < 4; ++m) {
        #pragma unroll
        for (int r = 0; r < 4; ++r) {
            const int co = co0 + wrow * 64 + m * 16 + 4 * (lane >> 4) + r;
            const float bv = ba[co];
            float* orow = out + ((size_t)(nb * CCH + co)) * PLANE + px0 + wcol * 64 + (lane & 15);
            #pragma unroll
            for (int nn = 0; nn < 4; ++nn)
                orow[nn * 16] = acc[m][nn][r] + bv;
        }
    }
}

extern "C" void kernel_launch(void* const* d_in, const int* in_sizes, int n_in,
                              void* d_out, int out_size, void* d_ws, size_t ws_size,
                              hipStream_t stream)
{
    const float* x  = (const float*)d_in[0];
    const float* w0 = (const float*)d_in[1];
    const float* b0 = (const float*)d_in[2];
    const float* w1 = (const float*)d_in[3];
    const float* b1 = (const float*)d_in[4];
    const float* w2 = (const float*)d_in[5];
    const float* b2 = (const float*)d_in[6];
    const float* w3 = (const float*)d_in[7];
    const float* b3 = (const float*)d_in[8];
    const float* w4 = (const float*)d_in[9];
    const float* b4 = (const float*)d_in[10];
    const float* w5 = (const float*)d_in[11];
    const float* b5 = (const float*)d_in[12];
    const float* w6 = (const float*)d_in[13];
    const float* b6 = (const float*)d_in[14];
    const float* wa = (const float*)d_in[15];
    const float* ba = (const float*)d_in[16];
    float* out = (float*)d_out;

    char* ws_base = (char*)d_ws;
    unsigned short* spB   = (unsigned short*)ws_base;                    // 50,331,648 B
    unsigned short* waB   = (unsigned short*)(ws_base + 50331648);       //    294,912 B
    unsigned short* fragV = (unsigned short*)(ws_base + 50626560);       //  3,145,728 B
    unsigned short* fragH = (unsigned short*)(ws_base + 53772288);       //  3,145,728 B
    float*          bsum  = (float*)         (ws_base + 56918016);       //      1,536 B

    prep<<<dim3(CCH + 144), 256, 0, stream>>>(
        w1, b1, w2, b2, w3, b3, w4, b4, w5, b5, w6, b6, wa, waB, fragV, fragH, bsum);
    dw_fused<<<dim3(NPLANES), 256, 0, stream>>>(
        x, w0, b0, fragV, fragH, bsum, spB);
    pw_mfma<<<dim3(NTOT / 128, CCH / 128), 256, 0, stream>>>(spB, waB, ba, out);
}

// Round 15
// 116.579 us; speedup vs baseline: 1.1133x; 1.0805x over previous
//
#include <hip/hip_runtime.h>
#include <cstdint>

#define NBATCH 16
#define CCH    384
#define HW     64
#define PLANE  (HW*HW)
#define NTOT   (NBATCH*PLANE)   // 65536 GEMM columns
#define NPLANES (NBATCH*CCH)    // 6144 dw blocks

typedef __attribute__((ext_vector_type(8))) short short8v;
typedef __attribute__((ext_vector_type(4))) float f32x4;

static __device__ __forceinline__ unsigned short f2bf(float f) {
    unsigned int x = __float_as_uint(f);
    unsigned int r = (x + 0x7fffu + ((x >> 16) & 1u)) >> 16;   // RTN-even
    return (unsigned short)r;
}
// packed f32x2 -> bf16x2 (low16 = a, high16 = b), RTE in HW (r9-verified)
static __device__ __forceinline__ unsigned int cvtpk(float a, float b) {
    unsigned int r;
    asm("v_cvt_pk_bf16_f32 %0, %1, %2" : "=v"(r) : "v"(a), "v"(b));
    return r;
}

// scheme-C rotation (r7-verified): closed mod 128, bijective, 16B-aligned
static __device__ __forceinline__ int rotC(int row) {
    return 2 * (row >> 4) + (row & 7);
}

// ---------------- prep kernel: band frags + bsum + wa_cvt (r11-verified) ----------------
__global__ __launch_bounds__(256)
void prep(const float* __restrict__ w1, const float* __restrict__ b1,
          const float* __restrict__ w2, const float* __restrict__ b2,
          const float* __restrict__ w3, const float* __restrict__ b3,
          const float* __restrict__ w4, const float* __restrict__ b4,
          const float* __restrict__ w5, const float* __restrict__ b5,
          const float* __restrict__ w6, const float* __restrict__ b6,
          const float* __restrict__ wa, unsigned short* __restrict__ waB,
          unsigned short* __restrict__ fragV, unsigned short* __restrict__ fragH,
          float* __restrict__ bsum)
{
    const int tid = threadIdx.x;
    if (blockIdx.x >= CCH) {
        const int i = (blockIdx.x - CCH) * 256 + tid;
        const float4 v = reinterpret_cast<const float4*>(wa)[i];
        ushort4 o;
        o.x = f2bf(v.x); o.y = f2bf(v.y); o.z = f2bf(v.z); o.w = f2bf(v.w);
        reinterpret_cast<ushort4*>(waB)[i] = o;
        return;
    }
    const int c = blockIdx.x;
    __shared__ float swh[21];
    __shared__ float swv[21];

    if (tid < 21) {                            // horizontal: w5(21)+w3(11)+w1(7)
        const int d = tid, dj = d - 10;
        float v = w5[c * 21 + d];
        if (dj >= -5 && dj <= 5) v += w3[c * 11 + dj + 5];
        if (dj >= -3 && dj <= 3) v += w1[c * 7  + dj + 3];
        swh[d] = v;
    } else if (tid >= 32 && tid < 53) {        // vertical: w6(21)+w4(11)+w2(7)
        const int d = tid - 32, di = d - 10;
        float v = w6[c * 21 + d];
        if (di >= -5 && di <= 5) v += w4[c * 11 + di + 5];
        if (di >= -3 && di <= 3) v += w2[c * 7  + di + 3];
        swv[d] = v;
    } else if (tid == 64) {
        bsum[c] = b1[c] + b2[c] + b3[c] + b4[c] + b5[c] + b6[c];
    }
    __syncthreads();

    const int lane = tid & 63;
    const int slot = tid >> 6;      // wid (fragV) / nt (fragH)
    const int l15  = lane & 15;
    const int l16  = lane >> 4;
    const int row  = slot * 16 + l15;           // arow / brow

    #pragma unroll
    for (int kk = 0; kk < 2; ++kk) {
        unsigned short uv[8], uh[8];
        #pragma unroll
        for (int j = 0; j < 8; ++j) {
            const int k = kk * 32 + l16 * 8 + j;
            const int d = k - row + 10;
            const bool ok = (unsigned)d < 21u;
            uv[j] = ok ? f2bf(swv[d]) : (unsigned short)0;
            uh[j] = ok ? f2bf(swh[d]) : (unsigned short)0;
        }
        const size_t idx = (size_t)(((c * 4 + slot) * 2 + kk) * 64 + lane) * 8;
        *reinterpret_cast<uint4*>(fragV + idx) = *reinterpret_cast<const uint4*>(uv);
        *reinterpret_cast<uint4*>(fragH + idx) = *reinterpret_cast<const uint4*>(uh);
    }
}

// ---------------- fused depthwise kernel v12 ----------------
// EXACT r11 (89.7us) structure with ONE change: weights/biases via wave-uniform
// global loads (SGPR path) -- sw0/sb LDS arrays and barrier B1 deleted.
// Conv is r11's flat per-granule-predicated 16-wide version (r14's row-level
// branch clustering regressed; flat predication lets all 30 loads issue in
// one burst). aV at entry; bH issued after LDS writes, held across B2 (r13).
__global__ __launch_bounds__(256)
void dw_fused(const float* __restrict__ x,
              const float* __restrict__ w0, const float* __restrict__ b0,
              const unsigned short* __restrict__ fragV,
              const unsigned short* __restrict__ fragH,
              const float* __restrict__ bsum,
              unsigned short* __restrict__ spB)
{
    __shared__ char ipR[64 * 128];
    __shared__ char ipT[64 * 128];

    const int tid = threadIdx.x;
    const int n   = blockIdx.x / CCH;
    const int c   = blockIdx.x % CCH;

    const int lane = tid & 63;
    const int wid  = tid >> 6;
    const int l15  = lane & 15;
    const int l16  = lane >> 4;

    // ---- issue aV frag loads immediately (r11) ----
    short8v aV[2];
    #pragma unroll
    for (int kk = 0; kk < 2; ++kk) {
        const size_t idx = (size_t)(((c * 4 + wid) * 2 + kk) * 64 + lane) * 8;
        aV[kk] = *reinterpret_cast<const short8v*>(fragV + idx);
    }

    // ---- uniform scalars (SGPR path; replaces sw0/sb LDS + B1) ----
    const float b0v = b0[c];
    const float bv1 = bsum[c];

    const int h  = tid >> 2;        // r11 conv mapping (coalesced)
    const int p  = tid & 3;
    const int ws = p << 4;

    // ---- 5x5 fp32 direct from global (r11-exact flat predication) ----
    float acc5[16];
    #pragma unroll
    for (int q = 0; q < 16; ++q) acc5[q] = b0v;
    {
        const float* xp = x + (size_t)blockIdx.x * PLANE;
        #pragma unroll
        for (int i = 0; i < 5; ++i) {
            const int rt = h + i - 2;
            float f[24];
            #pragma unroll
            for (int q = 0; q < 6; ++q) {
                const int c0 = ws - 4 + 4 * q;
                float4 v = make_float4(0.f, 0.f, 0.f, 0.f);
                if ((unsigned)rt < 64u && (unsigned)c0 <= 60u)
                    v = *reinterpret_cast<const float4*>(xp + rt * HW + c0);
                f[4*q+0] = v.x; f[4*q+1] = v.y; f[4*q+2] = v.z; f[4*q+3] = v.w;
            }
            #pragma unroll
            for (int j = 0; j < 5; ++j) {
                const float wg = w0[c * 25 + i * 5 + j];   // uniform -> s_load
                #pragma unroll
                for (int q = 0; q < 16; ++q) acc5[q] += f[q + j + 2] * wg;
            }
        }
    }
    // ---- pack bf16 (cvtpk) -> ipR vector + ipT transposed (r11-exact) ----
    {
        unsigned int wv[8];
        #pragma unroll
        for (int j = 0; j < 8; ++j) wv[j] = cvtpk(acc5[2*j], acc5[2*j+1]);
        const int rot = rotC(h);
        #pragma unroll
        for (int q = 0; q < 2; ++q) {
            const int off = ((ws << 1) + 16 * q + 16 * rot) & 127;
            uint4 u4 = make_uint4(wv[4*q+0], wv[4*q+1], wv[4*q+2], wv[4*q+3]);
            *reinterpret_cast<uint4*>(ipR + h * 128 + off) = u4;
        }
        #pragma unroll
        for (int k = 0; k < 16; ++k) {
            const int w   = ws + k;
            const int off = (2 * h + 16 * rotC(w)) & 127;
            *reinterpret_cast<unsigned short*>(ipT + w * 128 + off) =
                (unsigned short)(wv[k >> 1] >> (16 * (k & 1)));
        }
    }
    // ---- issue bH frag loads (r11 placement: after LDS writes, before B2) ----
    short8v bH[4][2];
    #pragma unroll
    for (int nt = 0; nt < 4; ++nt)
        #pragma unroll
        for (int kk = 0; kk < 2; ++kk) {
            const size_t idx = (size_t)(((c * 4 + nt) * 2 + kk) * 64 + lane) * 8;
            bH[nt][kk] = *reinterpret_cast<const short8v*>(fragH + idx);
        }
    __syncthreads();   // B2 (the only barrier)

    // ---- aH from ipR (r11-exact) ----
    const int arow = wid * 16 + l15;
    const int rotA = 16 * (2 * wid + (l15 & 7));
    short8v aH[2];
    #pragma unroll
    for (int kk = 0; kk < 2; ++kk) {
        const int off = (kk * 64 + l16 * 16 + rotA) & 127;
        aH[kk] = *reinterpret_cast<const short8v*>(ipR + arow * 128 + off);
    }
    unsigned short* op = spB + ((size_t)c * NBATCH + n) * PLANE;

    #pragma unroll
    for (int nt = 0; nt < 4; ++nt) {
        const int brow = nt * 16 + l15;
        const int rotB = 16 * (2 * nt + (l15 & 7));
        f32x4 acc = (f32x4){0.f, 0.f, 0.f, 0.f};
        #pragma unroll
        for (int kk = 0; kk < 2; ++kk) {
            const int off = (kk * 64 + l16 * 16 + rotB) & 127;
            const short8v bV = *reinterpret_cast<const short8v*>(ipT + brow * 128 + off);
            acc = __builtin_amdgcn_mfma_f32_16x16x32_bf16(aV[kk], bV, acc, 0, 0, 0);
            acc = __builtin_amdgcn_mfma_f32_16x16x32_bf16(aH[kk], bH[nt][kk], acc, 0, 0, 0);
        }
        #pragma unroll
        for (int r = 0; r < 4; ++r) {
            const int hh = wid * 16 + 4 * l16 + r;
            const int ww = nt * 16 + l15;
            op[hh * HW + ww] = f2bf(acc[r] + bv1);
        }
    }
}

// ---------------- 1x1 conv as bf16 MFMA GEMM (unchanged) ----------------
__global__ __launch_bounds__(256)
void pw_mfma(const unsigned short* __restrict__ spB,
             const unsigned short* __restrict__ waB,
             const float* __restrict__ ba, float* __restrict__ out)
{
    __shared__ unsigned short As[128 * 64];
    __shared__ unsigned short Bs[128 * 64];

    const int tid  = threadIdx.x;
    const int lane = tid & 63;
    const int wid  = tid >> 6;
    const int wrow = wid >> 1;
    const int wcol = wid & 1;

    const int co0  = blockIdx.y * 128;
    const int col0 = blockIdx.x * 128;

    f32x4 acc[4][4];
    #pragma unroll
    for (int m = 0; m < 4; ++m)
        #pragma unroll
        for (int nn = 0; nn < 4; ++nn) acc[m][nn] = (f32x4){0.f, 0.f, 0.f, 0.f};

    const char* waBb = (const char*)waB;

    for (int kt = 0; kt < 6; ++kt) {
        #pragma unroll
        for (int q = 0; q < 4; ++q) {
            const int L     = (wid * 4 + q) * 1024 + lane * 16;
            const int row   = L >> 7;
            const int kbyte = (L & 127) ^ ((row & 7) << 4);
            const void* src = (const void*)(waBb + (size_t)(co0 + row) * 768 + kt * 128 + kbyte);
            __builtin_amdgcn_global_load_lds(
                (const __attribute__((address_space(1))) void*)src,
                (__attribute__((address_space(3))) void*)((char*)As + (wid * 4 + q) * 1024),
                16, 0, 0);
        }

        #pragma unroll
        for (int j = 0; j < 2; ++j) {
            const int kloc  = j * 32 + 2 * (tid >> 4);
            const int cbase = 8 * (tid & 15);
            const unsigned int* gp =
                (const unsigned int*)(spB + (size_t)(kt * 64 + kloc) * NTOT + col0 + cbase);
            unsigned int g0[4], g1[4];
            *(uint4*)g0 = *(const uint4*)gp;
            *(uint4*)g1 = *(const uint4*)(gp + NTOT / 2);
            #pragma unroll
            for (int r = 0; r < 8; ++r) {
                const unsigned int w0v = g0[r >> 1], w1v = g1[r >> 1];
                const unsigned int lo = (r & 1) ? (w0v >> 16) : (w0v & 0xffffu);
                const unsigned int hi = (r & 1) ? (w1v >> 16) : (w1v & 0xffffu);
                const unsigned int val = lo | (hi << 16);
                const int colL = cbase + r;
                const int s    = (r ^ (tid & 7)) & 7;
                const int byte = colL * 128 + ((kloc * 2) ^ (s << 4));
                *(unsigned int*)((char*)Bs + byte) = val;
            }
        }
        __syncthreads();

        #pragma unroll
        for (int kk = 0; kk < 2; ++kk) {
            short8v aF[4], bF[4];
            const int kbyte = kk * 64 + (lane >> 4) * 16;
            #pragma unroll
            for (int m = 0; m < 4; ++m) {
                const int row = wrow * 64 + m * 16 + (lane & 15);
                aF[m] = *(const short8v*)((const char*)As + row * 128 + (kbyte ^ ((row & 7) << 4)));
            }
            #pragma unroll
            for (int nn = 0; nn < 4; ++nn) {
                const int col = wcol * 64 + nn * 16 + (lane & 15);
                const int s   = ((col & 7) ^ ((col >> 3) & 7)) << 4;
                bF[nn] = *(const short8v*)((const char*)Bs + col * 128 + (kbyte ^ s));
            }
            #pragma unroll
            for (int m = 0; m < 4; ++m)
                #pragma unroll
                for (int nn = 0; nn < 4; ++nn)
                    acc[m][nn] = __builtin_amdgcn_mfma_f32_16x16x32_bf16(
                        aF[m], bF[nn], acc[m][nn], 0, 0, 0);
        }
        __syncthreads();
    }

    const int nb  = col0 >> 12;
    const int px0 = col0 & 4095;
    #pragma unroll
    for (int m = 0; m < 4; ++m) {
        #pragma unroll
        for (int r = 0; r < 4; ++r) {
            const int co = co0 + wrow * 64 + m * 16 + 4 * (lane >> 4) + r;
            const float bv = ba[co];
            float* orow = out + ((size_t)(nb * CCH + co)) * PLANE + px0 + wcol * 64 + (lane & 15);
            #pragma unroll
            for (int nn = 0; nn < 4; ++nn)
                orow[nn * 16] = acc[m][nn][r] + bv;
        }
    }
}

extern "C" void kernel_launch(void* const* d_in, const int* in_sizes, int n_in,
                              void* d_out, int out_size, void* d_ws, size_t ws_size,
                              hipStream_t stream)
{
    const float* x  = (const float*)d_in[0];
    const float* w0 = (const float*)d_in[1];
    const float* b0 = (const float*)d_in[2];
    const float* w1 = (const float*)d_in[3];
    const float* b1 = (const float*)d_in[4];
    const float* w2 = (const float*)d_in[5];
    const float* b2 = (const float*)d_in[6];
    const float* w3 = (const float*)d_in[7];
    const float* b3 = (const float*)d_in[8];
    const float* w4 = (const float*)d_in[9];
    const float* b4 = (const float*)d_in[10];
    const float* w5 = (const float*)d_in[11];
    const float* b5 = (const float*)d_in[12];
    const float* w6 = (const float*)d_in[13];
    const float* b6 = (const float*)d_in[14];
    const float* wa = (const float*)d_in[15];
    const float* ba = (const float*)d_in[16];
    float* out = (float*)d_out;

    char* ws_base = (char*)d_ws;
    unsigned short* spB   = (unsigned short*)ws_base;                    // 50,331,648 B
    unsigned short* waB   = (unsigned short*)(ws_base + 50331648);       //    294,912 B
    unsigned short* fragV = (unsigned short*)(ws_base + 50626560);       //  3,145,728 B
    unsigned short* fragH = (unsigned short*)(ws_base + 53772288);       //  3,145,728 B
    float*          bsum  = (float*)         (ws_base + 56918016);       //      1,536 B

    prep<<<dim3(CCH + 144), 256, 0, stream>>>(
        w1, b1, w2, b2, w3, b3, w4, b4, w5, b5, w6, b6, wa, waB, fragV, fragH, bsum);
    dw_fused<<<dim3(NPLANES), 256, 0, stream>>>(
        x, w0, b0, fragV, fragH, bsum, spB);
    pw_mfma<<<dim3(NTOT / 128, CCH / 128), 256, 0, stream>>>(spB, waB, ba, out);
}

// Round 16
// 94.187 us; speedup vs baseline: 1.3779x; 1.2377x over previous
//
#include <hip/hip_runtime.h>
#include <cstdint>

#define NBATCH 16
#define CCH    384
#define HW     64
#define PLANE  (HW*HW)
#define NTOT   (NBATCH*PLANE)   // 65536 GEMM columns
#define NPLANES (NBATCH*CCH)    // 6144 dw blocks

typedef __attribute__((ext_vector_type(8))) short short8v;
typedef __attribute__((ext_vector_type(4))) float f32x4;

static __device__ __forceinline__ unsigned short f2bf(float f) {
    unsigned int x = __float_as_uint(f);
    unsigned int r = (x + 0x7fffu + ((x >> 16) & 1u)) >> 16;   // RTN-even
    return (unsigned short)r;
}
// packed f32x2 -> bf16x2 (low16 = a, high16 = b), RTE in HW (r9-verified)
static __device__ __forceinline__ unsigned int cvtpk(float a, float b) {
    unsigned int r;
    asm("v_cvt_pk_bf16_f32 %0, %1, %2" : "=v"(r) : "v"(a), "v"(b));
    return r;
}

// scheme-C rotation (r7-verified): closed mod 128, bijective, 16B-aligned
static __device__ __forceinline__ int rotC(int row) {
    return 2 * (row >> 4) + (row & 7);
}

// ---------------- prep kernel: band frags + bsum + wa_cvt (r11-verified) ----------------
__global__ __launch_bounds__(256)
void prep(const float* __restrict__ w1, const float* __restrict__ b1,
          const float* __restrict__ w2, const float* __restrict__ b2,
          const float* __restrict__ w3, const float* __restrict__ b3,
          const float* __restrict__ w4, const float* __restrict__ b4,
          const float* __restrict__ w5, const float* __restrict__ b5,
          const float* __restrict__ w6, const float* __restrict__ b6,
          const float* __restrict__ wa, unsigned short* __restrict__ waB,
          unsigned short* __restrict__ fragV, unsigned short* __restrict__ fragH,
          float* __restrict__ bsum)
{
    const int tid = threadIdx.x;
    if (blockIdx.x >= CCH) {
        const int i = (blockIdx.x - CCH) * 256 + tid;
        const float4 v = reinterpret_cast<const float4*>(wa)[i];
        ushort4 o;
        o.x = f2bf(v.x); o.y = f2bf(v.y); o.z = f2bf(v.z); o.w = f2bf(v.w);
        reinterpret_cast<ushort4*>(waB)[i] = o;
        return;
    }
    const int c = blockIdx.x;
    __shared__ float swh[21];
    __shared__ float swv[21];

    if (tid < 21) {                            // horizontal: w5(21)+w3(11)+w1(7)
        const int d = tid, dj = d - 10;
        float v = w5[c * 21 + d];
        if (dj >= -5 && dj <= 5) v += w3[c * 11 + dj + 5];
        if (dj >= -3 && dj <= 3) v += w1[c * 7  + dj + 3];
        swh[d] = v;
    } else if (tid >= 32 && tid < 53) {        // vertical: w6(21)+w4(11)+w2(7)
        const int d = tid - 32, di = d - 10;
        float v = w6[c * 21 + d];
        if (di >= -5 && di <= 5) v += w4[c * 11 + di + 5];
        if (di >= -3 && di <= 3) v += w2[c * 7  + di + 3];
        swv[d] = v;
    } else if (tid == 64) {
        bsum[c] = b1[c] + b2[c] + b3[c] + b4[c] + b5[c] + b6[c];
    }
    __syncthreads();

    const int lane = tid & 63;
    const int slot = tid >> 6;      // wid (fragV) / nt (fragH)
    const int l15  = lane & 15;
    const int l16  = lane >> 4;
    const int row  = slot * 16 + l15;           // arow / brow

    #pragma unroll
    for (int kk = 0; kk < 2; ++kk) {
        unsigned short uv[8], uh[8];
        #pragma unroll
        for (int j = 0; j < 8; ++j) {
            const int k = kk * 32 + l16 * 8 + j;
            const int d = k - row + 10;
            const bool ok = (unsigned)d < 21u;
            uv[j] = ok ? f2bf(swv[d]) : (unsigned short)0;
            uh[j] = ok ? f2bf(swh[d]) : (unsigned short)0;
        }
        const size_t idx = (size_t)(((c * 4 + slot) * 2 + kk) * 64 + lane) * 8;
        *reinterpret_cast<uint4*>(fragV + idx) = *reinterpret_cast<const uint4*>(uv);
        *reinterpret_cast<uint4*>(fragH + idx) = *reinterpret_cast<const uint4*>(uh);
    }
}

// ---------------- fused depthwise kernel v13 ----------------
// r15 (91us dw) with ONE change: x plane staged into LDS once via
// global_load_lds (async, 16KB, pre-swizzled SOURCE + linear dest, m173
// pattern) -- conv reads from LDS instead of 7.5x-amplified L1 traffic.
// Swizzle: LDS slot (row, gs) holds x granule (gs ^ (row&15)); staging src
//   = row*256 + (((tid&15)^(tid>>4))<<4)  [full-row coalesced];
// conv read byte = (rt&63)*256 + (((gq&15)^(rt&15))<<4), c0 = 4*gq;
// rt-dependent XOR spreads the wave's 16 rt values over 16 granule slots
// -> ~bank floor. OOB rt/gq wrap in-buffer, result cndmask'd to 0.
__global__ __launch_bounds__(256)
void dw_fused(const float* __restrict__ x,
              const float* __restrict__ w0, const float* __restrict__ b0,
              const unsigned short* __restrict__ fragV,
              const unsigned short* __restrict__ fragH,
              const float* __restrict__ bsum,
              unsigned short* __restrict__ spB)
{
    __shared__ char xs [64 * 256];   // 16 KB swizzled x plane
    __shared__ char ipR[64 * 128];
    __shared__ char ipT[64 * 128];

    const int tid = threadIdx.x;
    const int n   = blockIdx.x / CCH;
    const int c   = blockIdx.x % CCH;

    const int lane = tid & 63;
    const int wid  = tid >> 6;
    const int l15  = lane & 15;
    const int l16  = lane >> 4;

    // ---- stage x plane (async): linear LDS dest, swizzled global source ----
    {
        const char* xb = (const char*)(x + (size_t)blockIdx.x * PLANE);
        const int sg = (((tid & 15) ^ (tid >> 4)) & 15) << 4;   // src granule byte
        #pragma unroll
        for (int it = 0; it < 4; ++it) {
            const int row = it * 16 + (tid >> 4);
            const void* src = (const void*)(xb + row * 256 + sg);
            __builtin_amdgcn_global_load_lds(
                (const __attribute__((address_space(1))) void*)src,
                (__attribute__((address_space(3))) void*)(xs + it * 4096 + wid * 1024 + lane * 16),
                16, 0, 0);
        }
    }

    // ---- issue aV frag loads (r11/r15) ----
    short8v aV[2];
    #pragma unroll
    for (int kk = 0; kk < 2; ++kk) {
        const size_t idx = (size_t)(((c * 4 + wid) * 2 + kk) * 64 + lane) * 8;
        aV[kk] = *reinterpret_cast<const short8v*>(fragV + idx);
    }

    // ---- uniform scalars (SGPR path, r15) ----
    const float b0v = b0[c];
    const float bv1 = bsum[c];

    __syncthreads();   // B0: staging drained (vmcnt(0) before barrier)

    const int h  = tid >> 2;        // coalesced-conv thread mapping (r10 lesson)
    const int p  = tid & 3;
    const int ws = p << 4;

    // ---- 5x5 fp32 from LDS (flat per-granule predication, r15 form) ----
    float acc5[16];
    #pragma unroll
    for (int q = 0; q < 16; ++q) acc5[q] = b0v;
    {
        #pragma unroll
        for (int i = 0; i < 5; ++i) {
            const int rt  = h + i - 2;
            const bool rok = (unsigned)rt < 64u;
            const int rm  = rt & 63;
            const int rx  = rm & 15;
            float f[24];
            #pragma unroll
            for (int g = 0; g < 6; ++g) {
                const int gq  = 4 * p - 1 + g;          // c0 = 4*gq
                const bool ok = rok && ((unsigned)gq < 16u);
                const int byte = rm * 256 + (((gq & 15) ^ rx) << 4);
                const float4 v = *reinterpret_cast<const float4*>(xs + byte);
                f[4*g+0] = ok ? v.x : 0.f;
                f[4*g+1] = ok ? v.y : 0.f;
                f[4*g+2] = ok ? v.z : 0.f;
                f[4*g+3] = ok ? v.w : 0.f;
            }
            #pragma unroll
            for (int j = 0; j < 5; ++j) {
                const float wg = w0[c * 25 + i * 5 + j];   // uniform -> s_load
                #pragma unroll
                for (int q = 0; q < 16; ++q) acc5[q] += f[q + j + 2] * wg;
            }
        }
    }
    // ---- pack bf16 (cvtpk) -> ipR vector + ipT transposed (r11-exact) ----
    {
        unsigned int wv[8];
        #pragma unroll
        for (int j = 0; j < 8; ++j) wv[j] = cvtpk(acc5[2*j], acc5[2*j+1]);
        const int rot = rotC(h);
        #pragma unroll
        for (int q = 0; q < 2; ++q) {
            const int off = ((ws << 1) + 16 * q + 16 * rot) & 127;
            uint4 u4 = make_uint4(wv[4*q+0], wv[4*q+1], wv[4*q+2], wv[4*q+3]);
            *reinterpret_cast<uint4*>(ipR + h * 128 + off) = u4;
        }
        #pragma unroll
        for (int k = 0; k < 16; ++k) {
            const int w   = ws + k;
            const int off = (2 * h + 16 * rotC(w)) & 127;
            *reinterpret_cast<unsigned short*>(ipT + w * 128 + off) =
                (unsigned short)(wv[k >> 1] >> (16 * (k & 1)));
        }
    }
    // ---- issue bH frag loads (r11 placement), held across B2 (r13 lesson) ----
    short8v bH[4][2];
    #pragma unroll
    for (int nt = 0; nt < 4; ++nt)
        #pragma unroll
        for (int kk = 0; kk < 2; ++kk) {
            const size_t idx = (size_t)(((c * 4 + nt) * 2 + kk) * 64 + lane) * 8;
            bH[nt][kk] = *reinterpret_cast<const short8v*>(fragH + idx);
        }
    __syncthreads();   // B2

    // ---- aH from ipR (r11-exact) ----
    const int arow = wid * 16 + l15;
    const int rotA = 16 * (2 * wid + (l15 & 7));
    short8v aH[2];
    #pragma unroll
    for (int kk = 0; kk < 2; ++kk) {
        const int off = (kk * 64 + l16 * 16 + rotA) & 127;
        aH[kk] = *reinterpret_cast<const short8v*>(ipR + arow * 128 + off);
    }
    unsigned short* op = spB + ((size_t)c * NBATCH + n) * PLANE;

    #pragma unroll
    for (int nt = 0; nt < 4; ++nt) {
        const int brow = nt * 16 + l15;
        const int rotB = 16 * (2 * nt + (l15 & 7));
        f32x4 acc = (f32x4){0.f, 0.f, 0.f, 0.f};
        #pragma unroll
        for (int kk = 0; kk < 2; ++kk) {
            const int off = (kk * 64 + l16 * 16 + rotB) & 127;
            const short8v bV = *reinterpret_cast<const short8v*>(ipT + brow * 128 + off);
            acc = __builtin_amdgcn_mfma_f32_16x16x32_bf16(aV[kk], bV, acc, 0, 0, 0);
            acc = __builtin_amdgcn_mfma_f32_16x16x32_bf16(aH[kk], bH[nt][kk], acc, 0, 0, 0);
        }
        #pragma unroll
        for (int r = 0; r < 4; ++r) {
            const int hh = wid * 16 + 4 * l16 + r;
            const int ww = nt * 16 + l15;
            op[hh * HW + ww] = f2bf(acc[r] + bv1);
        }
    }
}

// ---------------- 1x1 conv as bf16 MFMA GEMM (unchanged) ----------------
__global__ __launch_bounds__(256)
void pw_mfma(const unsigned short* __restrict__ spB,
             const unsigned short* __restrict__ waB,
             const float* __restrict__ ba, float* __restrict__ out)
{
    __shared__ unsigned short As[128 * 64];
    __shared__ unsigned short Bs[128 * 64];

    const int tid  = threadIdx.x;
    const int lane = tid & 63;
    const int wid  = tid >> 6;
    const int wrow = wid >> 1;
    const int wcol = wid & 1;

    const int co0  = blockIdx.y * 128;
    const int col0 = blockIdx.x * 128;

    f32x4 acc[4][4];
    #pragma unroll
    for (int m = 0; m < 4; ++m)
        #pragma unroll
        for (int nn = 0; nn < 4; ++nn) acc[m][nn] = (f32x4){0.f, 0.f, 0.f, 0.f};

    const char* waBb = (const char*)waB;

    for (int kt = 0; kt < 6; ++kt) {
        #pragma unroll
        for (int q = 0; q < 4; ++q) {
            const int L     = (wid * 4 + q) * 1024 + lane * 16;
            const int row   = L >> 7;
            const int kbyte = (L & 127) ^ ((row & 7) << 4);
            const void* src = (const void*)(waBb + (size_t)(co0 + row) * 768 + kt * 128 + kbyte);
            __builtin_amdgcn_global_load_lds(
                (const __attribute__((address_space(1))) void*)src,
                (__attribute__((address_space(3))) void*)((char*)As + (wid * 4 + q) * 1024),
                16, 0, 0);
        }

        #pragma unroll
        for (int j = 0; j < 2; ++j) {
            const int kloc  = j * 32 + 2 * (tid >> 4);
            const int cbase = 8 * (tid & 15);
            const unsigned int* gp =
                (const unsigned int*)(spB + (size_t)(kt * 64 + kloc) * NTOT + col0 + cbase);
            unsigned int g0[4], g1[4];
            *(uint4*)g0 = *(const uint4*)gp;
            *(uint4*)g1 = *(const uint4*)(gp + NTOT / 2);
            #pragma unroll
            for (int r = 0; r < 8; ++r) {
                const unsigned int w0v = g0[r >> 1], w1v = g1[r >> 1];
                const unsigned int lo = (r & 1) ? (w0v >> 16) : (w0v & 0xffffu);
                const unsigned int hi = (r & 1) ? (w1v >> 16) : (w1v & 0xffffu);
                const unsigned int val = lo | (hi << 16);
                const int colL = cbase + r;
                const int s    = (r ^ (tid & 7)) & 7;
                const int byte = colL * 128 + ((kloc * 2) ^ (s << 4));
                *(unsigned int*)((char*)Bs + byte) = val;
            }
        }
        __syncthreads();

        #pragma unroll
        for (int kk = 0; kk < 2; ++kk) {
            short8v aF[4], bF[4];
            const int kbyte = kk * 64 + (lane >> 4) * 16;
            #pragma unroll
            for (int m = 0; m < 4; ++m) {
                const int row = wrow * 64 + m * 16 + (lane & 15);
                aF[m] = *(const short8v*)((const char*)As + row * 128 + (kbyte ^ ((row & 7) << 4)));
            }
            #pragma unroll
            for (int nn = 0; nn < 4; ++nn) {
                const int col = wcol * 64 + nn * 16 + (lane & 15);
                const int s   = ((col & 7) ^ ((col >> 3) & 7)) << 4;
                bF[nn] = *(const short8v*)((const char*)Bs + col * 128 + (kbyte ^ s));
            }
            #pragma unroll
            for (int m = 0; m < 4; ++m)
                #pragma unroll
                for (int nn = 0; nn < 4; ++nn)
                    acc[m][nn] = __builtin_amdgcn_mfma_f32_16x16x32_bf16(
                        aF[m], bF[nn], acc[m][nn], 0, 0, 0);
        }
        __syncthreads();
    }

    const int nb  = col0 >> 12;
    const int px0 = col0 & 4095;
    #pragma unroll
    for (int m = 0; m < 4; ++m) {
        #pragma unroll
        for (int r = 0; r < 4; ++r) {
            const int co = co0 + wrow * 64 + m * 16 + 4 * (lane >> 4) + r;
            const float bv = ba[co];
            float* orow = out + ((size_t)(nb * CCH + co)) * PLANE + px0 + wcol * 64 + (lane & 15);
            #pragma unroll
            for (int nn = 0; nn < 4; ++nn)
                orow[nn * 16] = acc[m][nn][r] + bv;
        }
    }
}

extern "C" void kernel_launch(void* const* d_in, const int* in_sizes, int n_in,
                              void* d_out, int out_size, void* d_ws, size_t ws_size,
                              hipStream_t stream)
{
    const float* x  = (const float*)d_in[0];
    const float* w0 = (const float*)d_in[1];
    const float* b0 = (const float*)d_in[2];
    const float* w1 = (const float*)d_in[3];
    const float* b1 = (const float*)d_in[4];
    const float* w2 = (const float*)d_in[5];
    const float* b2 = (const float*)d_in[6];
    const float* w3 = (const float*)d_in[7];
    const float* b3 = (const float*)d_in[8];
    const float* w4 = (const float*)d_in[9];
    const float* b4 = (const float*)d_in[10];
    const float* w5 = (const float*)d_in[11];
    const float* b5 = (const float*)d_in[12];
    const float* w6 = (const float*)d_in[13];
    const float* b6 = (const float*)d_in[14];
    const float* wa = (const float*)d_in[15];
    const float* ba = (const float*)d_in[16];
    float* out = (float*)d_out;

    char* ws_base = (char*)d_ws;
    unsigned short* spB   = (unsigned short*)ws_base;                    // 50,331,648 B
    unsigned short* waB   = (unsigned short*)(ws_base + 50331648);       //    294,912 B
    unsigned short* fragV = (unsigned short*)(ws_base + 50626560);       //  3,145,728 B
    unsigned short* fragH = (unsigned short*)(ws_base + 53772288);       //  3,145,728 B
    float*          bsum  = (float*)         (ws_base + 56918016);       //      1,536 B

    prep<<<dim3(CCH + 144), 256, 0, stream>>>(
        w1, b1, w2, b2, w3, b3, w4, b4, w5, b5, w6, b6, wa, waB, fragV, fragH, bsum);
    dw_fused<<<dim3(NPLANES), 256, 0, stream>>>(
        x, w0, b0, fragV, fragH, bsum, spB);
    pw_mfma<<<dim3(NTOT / 128, CCH / 128), 256, 0, stream>>>(spB, waB, ba, out);
}